// Round 1
// baseline (4360.613 us; speedup 1.0000x reference)
//
#include <hip/hip_runtime.h>
#include <hip/hip_bf16.h>
#include <cstddef>

// ---------------- types ----------------
typedef __attribute__((ext_vector_type(8))) short bh8;   // 8 x bf16 (4 VGPRs)
typedef __attribute__((ext_vector_type(4))) float f4acc; // MFMA accumulator

typedef const __attribute__((address_space(1))) void* gas_t;
typedef __attribute__((address_space(3))) void* las_t;
#define GLOAD_LDS16(G, L) __builtin_amdgcn_global_load_lds((gas_t)(G), (las_t)(L), 16, 0, 0)

__device__ __forceinline__ unsigned short f2bf(float f) {
  union { float f; unsigned u; } v; v.f = f;
  unsigned r = v.u + 0x7FFFu + ((v.u >> 16) & 1u);   // RNE
  return (unsigned short)(r >> 16);
}

// ---------------- f32 -> bf16 convert (n % 4 == 0) ----------------
__global__ void k_f32_to_bf16(const float* __restrict__ src, unsigned short* __restrict__ dst, int n4) {
  int i = blockIdx.x * blockDim.x + threadIdx.x;
  int stride = gridDim.x * blockDim.x;
  for (; i < n4; i += stride) {
    float4 v = reinterpret_cast<const float4*>(src)[i];
    ushort4 o;
    o.x = f2bf(v.x); o.y = f2bf(v.y); o.z = f2bf(v.z); o.w = f2bf(v.w);
    reinterpret_cast<ushort4*>(dst)[i] = o;
  }
}

// ---------------- Hproj = batch_H @ i2h_W^T  (fp32, [3328,512]x[512,512]) ----------------
// 64x64 tile, K-chunk 32 staged transposed in LDS (conflict-free b128 reads).
__global__ __launch_bounds__(256) void k_hproj(const float* __restrict__ A,
                                               const float* __restrict__ W,
                                               float* __restrict__ out) {
  __shared__ float As[32][68];
  __shared__ float Ws[32][68];
  int t = threadIdx.x;
  int m0 = blockIdx.x * 64, n0 = blockIdx.y * 64;
  int ti = t & 15, tj = t >> 4;  // ti -> col group (coalesced store), tj -> row group
  float acc[4][4] = {};
  for (int kc = 0; kc < 512; kc += 32) {
    __syncthreads();
#pragma unroll
    for (int q = 0; q < 2; ++q) {
      int f = q * 256 + t;
      int row = f >> 3, c4 = (f & 7) * 4;
      float4 a = *reinterpret_cast<const float4*>(A + (size_t)(m0 + row) * 512 + kc + c4);
      float4 w = *reinterpret_cast<const float4*>(W + (size_t)(n0 + row) * 512 + kc + c4);
      As[c4 + 0][row] = a.x; As[c4 + 1][row] = a.y; As[c4 + 2][row] = a.z; As[c4 + 3][row] = a.w;
      Ws[c4 + 0][row] = w.x; Ws[c4 + 1][row] = w.y; Ws[c4 + 2][row] = w.z; Ws[c4 + 3][row] = w.w;
    }
    __syncthreads();
#pragma unroll
    for (int k = 0; k < 32; ++k) {
      float4 a = *reinterpret_cast<const float4*>(&As[k][tj * 4]);  // 4 rows
      float4 w = *reinterpret_cast<const float4*>(&Ws[k][ti * 4]);  // 4 cols
      float ar[4] = {a.x, a.y, a.z, a.w};
      float wr[4] = {w.x, w.y, w.z, w.w};
#pragma unroll
      for (int i = 0; i < 4; ++i)
#pragma unroll
        for (int j = 0; j < 4; ++j) acc[i][j] += ar[i] * wr[j];
    }
  }
#pragma unroll
  for (int i = 0; i < 4; ++i) {
    float4 o = {acc[i][0], acc[i][1], acc[i][2], acc[i][3]};
    *reinterpret_cast<float4*>(out + (size_t)(m0 + tj * 4 + i) * 512 + n0 + ti * 4) = o;
  }
}

// ---------------- attention step: ph, e, softmax, context (one block per b) ----------------
__global__ __launch_bounds__(256) void k_attn(const float* __restrict__ Hproj,
                                              const float* __restrict__ bH,
                                              const float* __restrict__ h_in,
                                              const float* __restrict__ h2hW,
                                              const float* __restrict__ h2hb,
                                              const float* __restrict__ scoreW,
                                              float* __restrict__ ctx) {
  int b = blockIdx.x, t = threadIdx.x;
  __shared__ float sh[512];
  __shared__ float sph[512];
  __shared__ float se[32];
  __shared__ float sal[32];
  reinterpret_cast<float2*>(sh)[t] = reinterpret_cast<const float2*>(h_in + (size_t)b * 512)[t];
  __syncthreads();
  // ph[j] = h2h_b[j] + h . h2h_W[j,:]
  for (int j = t; j < 512; j += 256) {
    const float4* wr = reinterpret_cast<const float4*>(h2hW + (size_t)j * 512);
    const float4* hv = reinterpret_cast<const float4*>(sh);
    float a = 0.f;
#pragma unroll 8
    for (int k4 = 0; k4 < 128; ++k4) {
      float4 w = wr[k4], x = hv[k4];
      a += w.x * x.x + w.y * x.y + w.z * x.z + w.w * x.w;
    }
    sph[j] = a + h2hb[j];
  }
  __syncthreads();
  int lane = t & 63, wave = t >> 6;
  for (int tt = wave; tt < 26; tt += 4) {
    const float* hp = Hproj + ((size_t)b * 26 + tt) * 512;
    const float4* hp4 = reinterpret_cast<const float4*>(hp + lane * 8);
    const float4* ph4 = reinterpret_cast<const float4*>(sph + lane * 8);
    const float4* sc4 = reinterpret_cast<const float4*>(scoreW + lane * 8);
    float a = 0.f;
#pragma unroll
    for (int q = 0; q < 2; ++q) {
      float4 hv = hp4[q], pv = ph4[q], sv = sc4[q];
      a += tanhf(hv.x + pv.x) * sv.x + tanhf(hv.y + pv.y) * sv.y +
           tanhf(hv.z + pv.z) * sv.z + tanhf(hv.w + pv.w) * sv.w;
    }
#pragma unroll
    for (int off = 32; off; off >>= 1) a += __shfl_xor(a, off, 64);
    if (lane == 0) se[tt] = a;
  }
  __syncthreads();
  if (t < 64) {
    float v = (t < 26) ? se[t] : -1e30f;
    float m = v;
#pragma unroll
    for (int off = 32; off; off >>= 1) m = fmaxf(m, __shfl_xor(m, off, 64));
    float p = (t < 26) ? expf(v - m) : 0.f;
    float s = p;
#pragma unroll
    for (int off = 32; off; off >>= 1) s += __shfl_xor(s, off, 64);
    if (t < 26) sal[t] = p / s;
  }
  __syncthreads();
  float2 acc = make_float2(0.f, 0.f);
  const float* bhb = bH + (size_t)b * 26 * 512;
#pragma unroll 1
  for (int tt = 0; tt < 26; ++tt) {
    float a = sal[tt];
    float2 v = reinterpret_cast<const float2*>(bhb + (size_t)tt * 512)[t];
    acc.x += a * v.x; acc.y += a * v.y;
  }
  reinterpret_cast<float2*>(ctx + (size_t)b * 512)[t] = acc;
}

// ---------------- gates GEMM + LSTM pointwise ----------------
// grid (32 u-chunks, 8 b-chunks); block: 64 gate-rows (4 gates x 16 u) x 16 b.
__global__ __launch_bounds__(256) void k_gates(const float* __restrict__ ctx,
                                               const float* __restrict__ h_in,
                                               const float* __restrict__ c_in,
                                               const float* __restrict__ Wih,
                                               const float* __restrict__ Whh,
                                               const float* __restrict__ bih,
                                               const float* __restrict__ bhh,
                                               const int* __restrict__ text,
                                               float* __restrict__ h_out,
                                               float* __restrict__ c_out,
                                               unsigned short* __restrict__ ohb,
                                               int step) {
  __shared__ float sg[64][17];
  int t = threadIdx.x, lane = t & 63, wave = t >> 6;
  int uc = blockIdx.x, bc = blockIdx.y;
  int u = lane & 15, gate = lane >> 4;
  int jg = gate * 512 + uc * 16 + u;
  const float* wih_row = Wih + (size_t)jg * 550;
  const float* whh_row = Whh + (size_t)jg * 512;
  int b0 = bc * 16 + wave * 4;
  const float* xb0 = ctx + (size_t)__builtin_amdgcn_readfirstlane(b0 + 0) * 512;
  const float* xb1 = ctx + (size_t)__builtin_amdgcn_readfirstlane(b0 + 1) * 512;
  const float* xb2 = ctx + (size_t)__builtin_amdgcn_readfirstlane(b0 + 2) * 512;
  const float* xb3 = ctx + (size_t)__builtin_amdgcn_readfirstlane(b0 + 3) * 512;
  float a0 = 0.f, a1 = 0.f, a2 = 0.f, a3 = 0.f;
#pragma unroll 4
  for (int k4 = 0; k4 < 128; ++k4) {
    float2 w0 = *reinterpret_cast<const float2*>(wih_row + k4 * 4);      // row stride 550 -> 8B aligned
    float2 w1 = *reinterpret_cast<const float2*>(wih_row + k4 * 4 + 2);
    float4 x0 = reinterpret_cast<const float4*>(xb0)[k4];
    float4 x1 = reinterpret_cast<const float4*>(xb1)[k4];
    float4 x2 = reinterpret_cast<const float4*>(xb2)[k4];
    float4 x3 = reinterpret_cast<const float4*>(xb3)[k4];
    a0 += w0.x * x0.x + w0.y * x0.y + w1.x * x0.z + w1.y * x0.w;
    a1 += w0.x * x1.x + w0.y * x1.y + w1.x * x1.z + w1.y * x1.w;
    a2 += w0.x * x2.x + w0.y * x2.y + w1.x * x2.z + w1.y * x2.w;
    a3 += w0.x * x3.x + w0.y * x3.y + w1.x * x3.z + w1.y * x3.w;
  }
  const float* yb0 = h_in + (size_t)__builtin_amdgcn_readfirstlane(b0 + 0) * 512;
  const float* yb1 = h_in + (size_t)__builtin_amdgcn_readfirstlane(b0 + 1) * 512;
  const float* yb2 = h_in + (size_t)__builtin_amdgcn_readfirstlane(b0 + 2) * 512;
  const float* yb3 = h_in + (size_t)__builtin_amdgcn_readfirstlane(b0 + 3) * 512;
#pragma unroll 4
  for (int k4 = 0; k4 < 128; ++k4) {
    float4 w = reinterpret_cast<const float4*>(whh_row)[k4];
    float4 x0 = reinterpret_cast<const float4*>(yb0)[k4];
    float4 x1 = reinterpret_cast<const float4*>(yb1)[k4];
    float4 x2 = reinterpret_cast<const float4*>(yb2)[k4];
    float4 x3 = reinterpret_cast<const float4*>(yb3)[k4];
    a0 += w.x * x0.x + w.y * x0.y + w.z * x0.z + w.w * x0.w;
    a1 += w.x * x1.x + w.y * x1.y + w.z * x1.z + w.w * x1.w;
    a2 += w.x * x2.x + w.y * x2.y + w.z * x2.z + w.w * x2.w;
    a3 += w.x * x3.x + w.y * x3.y + w.z * x3.z + w.w * x3.w;
  }
  float bsum = bih[jg] + bhh[jg];
  a0 += bsum + wih_row[512 + text[(b0 + 0) * 26 + step]];
  a1 += bsum + wih_row[512 + text[(b0 + 1) * 26 + step]];
  a2 += bsum + wih_row[512 + text[(b0 + 2) * 26 + step]];
  a3 += bsum + wih_row[512 + text[(b0 + 3) * 26 + step]];
  sg[lane][wave * 4 + 0] = a0;
  sg[lane][wave * 4 + 1] = a1;
  sg[lane][wave * 4 + 2] = a2;
  sg[lane][wave * 4 + 3] = a3;
  __syncthreads();
  // LSTM pointwise: thread -> (u_loc, b_loc)
  int ul = t & 15, bl = t >> 4;
  float gi = sg[ul][bl];
  float gf = sg[16 + ul][bl];
  float gg = sg[32 + ul][bl];
  float go = sg[48 + ul][bl];
  int b = bc * 16 + bl;
  int ug = uc * 16 + ul;
  float c_old = c_in[(size_t)b * 512 + ug];
  float ii = 1.f / (1.f + expf(-gi));
  float ff = 1.f / (1.f + expf(-gf));
  float oo = 1.f / (1.f + expf(-go));
  float cn = ff * c_old + ii * tanhf(gg);
  float hn = oo * tanhf(cn);
  c_out[(size_t)b * 512 + ug] = cn;
  h_out[(size_t)b * 512 + ug] = hn;
  ohb[((size_t)b * 26 + step) * 512 + ug] = f2bf(hn);
}

// ---------------- bf16 MFMA head GEMM: C[3328,N] = A[3328,512] @ W[N,512]^T + bias ----------------
// m97-style: 128x128 tile, BK=32, global_load_lds width 16, 4 waves (2x2), 4x4 frags each.
__global__ __launch_bounds__(256) void k_head_gemm(const unsigned short* __restrict__ A,
                                                   const unsigned short* __restrict__ Wb,
                                                   const float* __restrict__ bias,
                                                   float* __restrict__ C, int N) {
  __shared__ __align__(16) unsigned short As[128 * 32];
  __shared__ __align__(16) unsigned short Bs[128 * 32];
  int t = threadIdx.x, lane = t & 63, wave = t >> 6;
  int m0 = blockIdx.x * 128;   // x = M-tile so consecutive blocks share the B tile
  int n0 = blockIdx.y * 128;
  int wr = (wave >> 1) * 64, wc = (wave & 1) * 64;
  f4acc acc[4][4] = {};
  int f0 = t, f1 = 256 + t;
  int rowA0 = f0 >> 2, chA0 = (f0 & 3) * 8;
  int rowA1 = f1 >> 2, chA1 = (f1 & 3) * 8;
  int rB0 = n0 + rowA0; if (rB0 > N - 1) rB0 = N - 1;   // clamp for N edge (store masked)
  int rB1 = n0 + rowA1; if (rB1 > N - 1) rB1 = N - 1;
  const unsigned short* Ag0 = A + (size_t)(m0 + rowA0) * 512 + chA0;
  const unsigned short* Ag1 = A + (size_t)(m0 + rowA1) * 512 + chA1;
  const unsigned short* Bg0 = Wb + (size_t)rB0 * 512 + chA0;
  const unsigned short* Bg1 = Wb + (size_t)rB1 * 512 + chA1;
  int la = lane & 15, ka = (lane >> 4) * 8;
  for (int kt = 0; kt < 16; ++kt) {
    int ko = kt * 32;
    __syncthreads();
    GLOAD_LDS16(Ag0 + ko, As + f0 * 8);
    GLOAD_LDS16(Ag1 + ko, As + f1 * 8);
    GLOAD_LDS16(Bg0 + ko, Bs + f0 * 8);
    GLOAD_LDS16(Bg1 + ko, Bs + f1 * 8);
    __syncthreads();
    bh8 av[4], bv[4];
#pragma unroll
    for (int m = 0; m < 4; ++m)
      av[m] = *reinterpret_cast<const bh8*>(As + (wr + m * 16 + la) * 32 + ka);
#pragma unroll
    for (int n = 0; n < 4; ++n)
      bv[n] = *reinterpret_cast<const bh8*>(Bs + (wc + n * 16 + la) * 32 + ka);
#pragma unroll
    for (int m = 0; m < 4; ++m)
#pragma unroll
      for (int n = 0; n < 4; ++n)
        acc[m][n] = __builtin_amdgcn_mfma_f32_16x16x32_bf16(av[m], bv[n], acc[m][n], 0, 0, 0);
  }
  int r4 = (lane >> 4) * 4;
#pragma unroll
  for (int n = 0; n < 4; ++n) {
    int col = n0 + wc + n * 16 + la;
    if (col < N) {
      float bvl = bias[col];
#pragma unroll
      for (int m = 0; m < 4; ++m) {
        int row = m0 + wr + m * 16 + r4;
#pragma unroll
        for (int r = 0; r < 4; ++r)
          C[(size_t)(row + r) * N + col] = acc[m][n][r] + bvl;
      }
    }
  }
}

// ---------------- launcher ----------------
extern "C" void kernel_launch(void* const* d_in, const int* in_sizes, int n_in,
                              void* d_out, int out_size, void* d_ws, size_t ws_size,
                              hipStream_t stream) {
  (void)in_sizes; (void)n_in; (void)out_size; (void)ws_size;
  const float* batch_H = (const float*)d_in[0];
  const int*   text    = (const int*)d_in[1];
  const float* i2h_W   = (const float*)d_in[2];
  const float* h2h_W   = (const float*)d_in[3];
  const float* h2h_b   = (const float*)d_in[4];
  const float* score_W = (const float*)d_in[5];
  const float* rnn_Wih = (const float*)d_in[6];
  const float* rnn_bih = (const float*)d_in[7];
  const float* rnn_Whh = (const float*)d_in[8];
  const float* rnn_bhh = (const float*)d_in[9];
  const float* char_W  = (const float*)d_in[10];
  const float* char_b  = (const float*)d_in[11];
  const float* bpe_W   = (const float*)d_in[12];
  const float* bpe_b   = (const float*)d_in[13];
  const float* wp_W    = (const float*)d_in[14];
  const float* wp_b    = (const float*)d_in[15];
  float* out = (float*)d_out;

  char* ws = (char*)d_ws;
  size_t off = 0;
  auto alloc = [&](size_t bytes) { void* p = ws + off; off = (off + bytes + 255) & ~(size_t)255; return p; };
  float* Hproj = (float*)alloc(3328ull * 512 * 4);
  float* h0    = (float*)alloc(128 * 512 * 4);
  float* h1    = (float*)alloc(128 * 512 * 4);
  float* c0    = (float*)alloc(128 * 512 * 4);
  float* c1    = (float*)alloc(128 * 512 * 4);
  float* ctx   = (float*)alloc(128 * 512 * 4);
  unsigned short* ohb     = (unsigned short*)alloc(3328ull * 512 * 2);
  unsigned short* wb_char = (unsigned short*)alloc(38ull * 512 * 2);
  unsigned short* wb_bpe  = (unsigned short*)alloc(50257ull * 512 * 2);
  unsigned short* wb_wp   = (unsigned short*)alloc(30522ull * 512 * 2);

  hipMemsetAsync(h0, 0, 128 * 512 * 4, stream);
  hipMemsetAsync(c0, 0, 128 * 512 * 4, stream);

  k_f32_to_bf16<<<64, 256, 0, stream>>>(char_W, wb_char, 38 * 512 / 4);
  k_f32_to_bf16<<<2048, 256, 0, stream>>>(bpe_W, wb_bpe, 50257 * 512 / 4);
  k_f32_to_bf16<<<2048, 256, 0, stream>>>(wp_W, wb_wp, 30522 * 512 / 4);

  k_hproj<<<dim3(52, 8), 256, 0, stream>>>(batch_H, i2h_W, Hproj);

  float* hbuf[2] = {h0, h1};
  float* cbuf[2] = {c0, c1};
  for (int s = 0; s < 26; ++s) {
    const float* hin = hbuf[s & 1];
    float* hout      = hbuf[(s + 1) & 1];
    const float* cin = cbuf[s & 1];
    float* cout      = cbuf[(s + 1) & 1];
    k_attn<<<128, 256, 0, stream>>>(Hproj, batch_H, hin, h2h_W, h2h_b, score_W, ctx);
    k_gates<<<dim3(32, 8), 256, 0, stream>>>(ctx, hin, cin, rnn_Wih, rnn_Whh, rnn_bih, rnn_bhh,
                                             text, hout, cout, ohb, s);
  }

  float* out_char = out;
  float* out_bpe  = out + 3328ull * 38;
  float* out_wp   = out_bpe + 3328ull * 50257;
  k_head_gemm<<<dim3(26, 1),   256, 0, stream>>>(ohb, wb_char, char_b, out_char, 38);
  k_head_gemm<<<dim3(26, 393), 256, 0, stream>>>(ohb, wb_bpe,  bpe_b,  out_bpe,  50257);
  k_head_gemm<<<dim3(26, 239), 256, 0, stream>>>(ohb, wb_wp,   wp_b,   out_wp,   30522);
}